// Round 3
// baseline (804.438 us; speedup 1.0000x reference)
//
#include <hip/hip_runtime.h>
#include <hip/hip_cooperative_groups.h>
#include <math.h>

namespace cg = cooperative_groups;

#define BB 32
#define HH 12
#define CC 512
#define DD 768
#define MM 8
#define NERD 6
#define NCLS 97
#define KTOT 1542        // 2*D + NER
#define KMAIN 1536       // 2*D
#define OFFS 1
#define KCH 192          // K-chunk staged in LDS (8 chunks * 192 = 1536)
#define APAD 194         // LDS row stride: (194*b+k)%32 = (2b+k)%32 -> 2-way (free)
#define NTHR 256

// ---------------------------------------------------------------------------
// ws layout (float offsets):
//   partial [B*H*C]   @ 0         per-(b,h) att product (no atomics, no memset)
//   Afull   [B*1536]  @ 196608    concat(hs, unnormalized rs) per b
//   Sb      [B]       @ 245760    sum_c raw ht_att
//   fbuf    [2*B*D]   @ 245792    tanh'd head (e=0) / tail (e=1)
// total ~295k floats = 1.18 MB
// ---------------------------------------------------------------------------

// Phase A: 864 grid-stride units.
//  u<768: (b,h,half) att product -> partial.  u<800: logsumexp -> Afull hs.
//  u<864: zero Afull rs half + Sb.
__device__ __forceinline__ void phaseA(const float* __restrict__ att,
                                       const float* __restrict__ seq,
                                       const int* __restrict__ epos,
                                       float* __restrict__ partial,
                                       float* __restrict__ Afull,
                                       float* __restrict__ Sb) {
    __shared__ int pos[16];
    int tid = threadIdx.x;
    for (int u = blockIdx.x; u < 864; u += gridDim.x) {
        int b = (u < 768) ? (u / 24) : ((u < 800) ? (u - 768) : (u - 800));
        __syncthreads();
        if (tid < 16) pos[tid] = epos[b * 16 + tid] + OFFS;
        __syncthreads();
        if (u < 768) {
            int rem = u - b * 24;
            int h = rem >> 1, half = rem & 1;
            int c = half * 256 + tid;
            const float* base = att + ((size_t)(b * HH + h)) * CC * CC + c;
            float a0 = 0.f, a1 = 0.f;
#pragma unroll
            for (int m = 0; m < MM; m++) {
                a0 += base[(size_t)pos[m] * CC];
                a1 += base[(size_t)pos[MM + m] * CC];
            }
            partial[((size_t)(b * HH + h)) * CC + c] = a0 * a1 * (1.0f / (MM * MM * HH));
        } else if (u < 800) {
            if (tid < 192) {
                float xs0[MM], xs1[MM], xs2[MM], xs3[MM];
#pragma unroll
                for (int m = 0; m < MM; m++) {
                    float4 v = *(const float4*)&seq[((size_t)b * CC + pos[m]) * DD + tid * 4];
                    xs0[m] = v.x; xs1[m] = v.y; xs2[m] = v.z; xs3[m] = v.w;
                }
                float o[4];
                float* xs[4] = {xs0, xs1, xs2, xs3};
#pragma unroll
                for (int comp = 0; comp < 4; comp++) {
                    float mx = xs[comp][0];
#pragma unroll
                    for (int m = 1; m < MM; m++) mx = fmaxf(mx, xs[comp][m]);
                    float se = 0.f;
#pragma unroll
                    for (int m = 0; m < MM; m++) se += expf(xs[comp][m] - mx);
                    o[comp] = logf(se) + mx;
                }
                float4 hv = {o[0], o[1], o[2], o[3]};
                *(float4*)&Afull[(size_t)b * KMAIN + tid * 4] = hv;
            }
        } else {
            float* ap = Afull + (size_t)b * KMAIN + DD;
            ap[tid] = 0.f; ap[tid + 256] = 0.f; ap[tid + 512] = 0.f;
            if (tid == 0) Sb[b] = 0.f;
        }
    }
}

// Phase B: 1024 units (b, cc of 16 c's): w[c] = sum_h partial; rs += seq*w
// (atomic into Afull rs half); Sb += sum_c w (atomic).
__device__ __forceinline__ void phaseB(const float* __restrict__ seq,
                                       const float* __restrict__ partial,
                                       float* __restrict__ Afull,
                                       float* __restrict__ Sb) {
    __shared__ float wsb[16];
    int tid = threadIdx.x;
    for (int u = blockIdx.x; u < 1024; u += gridDim.x) {
        int b = u >> 5, cc = u & 31;
        int c0 = cc * 16;
        __syncthreads();
        if (tid < 16) {
            float s = 0.f;
#pragma unroll
            for (int h = 0; h < HH; h++) s += partial[((size_t)(b * HH + h)) * CC + c0 + tid];
            wsb[tid] = s;
        }
        __syncthreads();
        if (tid < 192) {
            float4 acc = {0.f, 0.f, 0.f, 0.f};
            const float* sp = seq + ((size_t)(b * CC + c0)) * DD + tid * 4;
#pragma unroll 4
            for (int ci = 0; ci < 16; ci++) {
                float w = wsb[ci];
                float4 v = *(const float4*)(sp + (size_t)ci * DD);
                acc.x += v.x * w; acc.y += v.y * w; acc.z += v.z * w; acc.w += v.w * w;
            }
            float* ap = &Afull[(size_t)b * KMAIN + DD + tid * 4];
            atomicAdd(ap + 0, acc.x); atomicAdd(ap + 1, acc.y);
            atomicAdd(ap + 2, acc.z); atomicAdd(ap + 3, acc.w);
        }
        if (tid == 0) {
            float s = 0.f;
#pragma unroll
            for (int i = 0; i < 16; i++) s += wsb[i];
            atomicAdd(&Sb[b], s);
        }
    }
}

// Phase C: 192 units (jt of 8 j's, e). Head/tail GEMM with LDS-staged A;
// rs half normalized by 1/(Sb+1e-5) during staging; ner/bias/tanh epilogue.
__device__ __forceinline__ void phaseC(const float* __restrict__ Afull,
                                       const float* __restrict__ Sb,
                                       const float* __restrict__ ner,
                                       const float* __restrict__ Wh,
                                       const float* __restrict__ bh,
                                       const float* __restrict__ Wt,
                                       const float* __restrict__ bt,
                                       float* __restrict__ fbuf) {
    __shared__ float invS[BB];
    __shared__ float A[BB][APAD];
    int tid = threadIdx.x;
    for (int u = blockIdx.x; u < 192; u += gridDim.x) {
        int jt = u >> 1, e = u & 1;
        __syncthreads();
        if (tid < BB) invS[tid] = 1.0f / (Sb[tid] + 1e-5f);
        __syncthreads();
        int b = tid & 31, jq = tid >> 5;
        int j = jt * 8 + jq;
        const float* W = e ? Wt : Wh;
        float acc = 0.f;
        for (int ch = 0; ch < 8; ch++) {
            for (int i = tid; i < 32 * KCH; i += NTHR) {
                int bb = i / KCH, kk = i - bb * KCH;
                int k = ch * KCH + kk;
                float v = Afull[(size_t)bb * KMAIN + k];
                if (k >= DD) v *= invS[bb];
                A[bb][kk] = v;
            }
            __syncthreads();
            const float* Wrow = W + (size_t)j * KTOT + ch * KCH;
#pragma unroll 8
            for (int kk = 0; kk < KCH; kk += 2) {
                float2 w = *(const float2*)&Wrow[kk];
                float2 a = *(const float2*)&A[b][kk];
                acc += a.x * w.x + a.y * w.y;
            }
            __syncthreads();
        }
        const float* nr = ner + (b * 2 + e) * NERD;
        const float* Wn = W + (size_t)j * KTOT + KMAIN;
#pragma unroll
        for (int q = 0; q < NERD; q++) acc += nr[q] * Wn[q];
        const float* bias = e ? bt : bh;
        fbuf[(size_t)(e * 32 + b) * DD + j] = tanhf(acc + bias[j]);
    }
}

// Phase D: 97 units (one class n). Bilinear + final matmul.
__device__ __forceinline__ void phaseD(const float* __restrict__ fbuf,
                                       const float* __restrict__ Wbil,
                                       const float* __restrict__ bbil,
                                       float* __restrict__ out) {
    __shared__ float part[BB * 9];
    int tid = threadIdx.x;
    for (int n = blockIdx.x; n < NCLS; n += gridDim.x) {
        __syncthreads();
        int g = tid & 7, b = tid >> 3;
        const float* hsf = fbuf + b * DD;
        const float* tsf = fbuf + (32 + b) * DD;
        const float* W = Wbil + (size_t)n * (DD * 8);
        float acc = 0.f;
        for (int t = 0; t < 12; t++) {
            int f = g + 8 * t;
            float4 h0 = *(const float4*)&hsf[f * 8];
            float4 h1 = *(const float4*)&hsf[f * 8 + 4];
            float4 t0 = *(const float4*)&tsf[f * 8];
            float4 t1 = *(const float4*)&tsf[f * 8 + 4];
            float hv[8] = {h0.x, h0.y, h0.z, h0.w, h1.x, h1.y, h1.z, h1.w};
            float tv[8] = {t0.x, t0.y, t0.z, t0.w, t1.x, t1.y, t1.z, t1.w};
            const float* wf = W + f * 64;
#pragma unroll
            for (int i = 0; i < 8; i++) {
                float4 w0 = *(const float4*)&wf[i * 8];
                float4 w1 = *(const float4*)&wf[i * 8 + 4];
                float dot = tv[0] * w0.x + tv[1] * w0.y + tv[2] * w0.z + tv[3] * w0.w
                          + tv[4] * w1.x + tv[5] * w1.y + tv[6] * w1.z + tv[7] * w1.w;
                acc += hv[i] * dot;
            }
        }
        part[b * 9 + g] = acc;
        __syncthreads();
        if (g == 0) {
            float s = 0.f;
#pragma unroll
            for (int i = 0; i < 8; i++) s += part[b * 9 + i];
            out[b * NCLS + n] = s + bbil[n];
        }
    }
}

__global__ void __launch_bounds__(NTHR, 2) k_fused(
    const float* __restrict__ seq, const float* __restrict__ att,
    const float* __restrict__ ner,
    const float* __restrict__ Wh, const float* __restrict__ bh,
    const float* __restrict__ Wt, const float* __restrict__ bt,
    const float* __restrict__ Wbil, const float* __restrict__ bbil,
    const int* __restrict__ epos,
    float* __restrict__ partial, float* __restrict__ Afull,
    float* __restrict__ Sb, float* __restrict__ fbuf,
    float* __restrict__ out) {
    cg::grid_group grid = cg::this_grid();
    phaseA(att, seq, epos, partial, Afull, Sb);
    grid.sync();
    phaseB(seq, partial, Afull, Sb);
    grid.sync();
    phaseC(Afull, Sb, ner, Wh, bh, Wt, bt, fbuf);
    grid.sync();
    phaseD(fbuf, Wbil, bbil, out);
}

// Non-cooperative fallback wrappers (same math, 4 launches).
__global__ void __launch_bounds__(NTHR) kA(const float* att, const float* seq,
                                           const int* epos, float* partial,
                                           float* Afull, float* Sb) {
    phaseA(att, seq, epos, partial, Afull, Sb);
}
__global__ void __launch_bounds__(NTHR) kB(const float* seq, const float* partial,
                                           float* Afull, float* Sb) {
    phaseB(seq, partial, Afull, Sb);
}
__global__ void __launch_bounds__(NTHR) kC(const float* Afull, const float* Sb,
                                           const float* ner, const float* Wh,
                                           const float* bh, const float* Wt,
                                           const float* bt, float* fbuf) {
    phaseC(Afull, Sb, ner, Wh, bh, Wt, bt, fbuf);
}
__global__ void __launch_bounds__(NTHR) kD(const float* fbuf, const float* Wbil,
                                           const float* bbil, float* out) {
    phaseD(fbuf, Wbil, bbil, out);
}

extern "C" void kernel_launch(void* const* d_in, const int* in_sizes, int n_in,
                              void* d_out, int out_size, void* d_ws, size_t ws_size,
                              hipStream_t stream) {
    const float* seq  = (const float*)d_in[0];
    const float* att  = (const float*)d_in[1];
    const float* ner  = (const float*)d_in[2];
    const float* Wh   = (const float*)d_in[3];
    const float* bh   = (const float*)d_in[4];
    const float* Wt   = (const float*)d_in[5];
    const float* bt   = (const float*)d_in[6];
    const float* Wbil = (const float*)d_in[7];
    const float* bbil = (const float*)d_in[8];
    const int*   epos = (const int*)d_in[9];
    float* out = (float*)d_out;
    float* ws = (float*)d_ws;

    float* partial = ws;             // 32*12*512 = 196608
    float* Afull   = ws + 196608;    // 32*1536  = 49152
    float* Sb      = ws + 245760;    // 32
    float* fbuf    = ws + 245792;    // 2*32*768 = 49152

    int mb = 0;
    hipOccupancyMaxActiveBlocksPerMultiprocessor(&mb, k_fused, NTHR, 0);
    bool coop_ok = false;
    if (mb >= 1) {
        int bpc = mb > 2 ? 2 : mb;
        dim3 grid(256 * bpc);
        void* args[] = {(void*)&seq, (void*)&att, (void*)&ner, (void*)&Wh, (void*)&bh,
                        (void*)&Wt, (void*)&bt, (void*)&Wbil, (void*)&bbil, (void*)&epos,
                        (void*)&partial, (void*)&Afull, (void*)&Sb, (void*)&fbuf, (void*)&out};
        coop_ok = (hipLaunchCooperativeKernel(k_fused, grid, dim3(NTHR), args, 0, stream)
                   == hipSuccess);
    }
    if (!coop_ok) {
        kA<<<864, NTHR, 0, stream>>>(att, seq, epos, partial, Afull, Sb);
        kB<<<1024, NTHR, 0, stream>>>(seq, partial, Afull, Sb);
        kC<<<192, NTHR, 0, stream>>>(Afull, Sb, ner, Wh, bh, Wt, bt, fbuf);
        kD<<<97, NTHR, 0, stream>>>(fbuf, Wbil, bbil, out);
    }
}